// Round 2
// baseline (512.579 us; speedup 1.0000x reference)
//
#include <hip/hip_runtime.h>
#include <hip/hip_fp16.h>
#include <math.h>

#define N_EMB   1000000
#define D       64
#define E_PAIRS 65536
#define K_NEG   16
#define P_TOTAL (E_PAIRS * (K_NEG + 1))   /* 1114112 */
#define PPB     128                        /* pairs per block (4 waves x 32 pairs) */

typedef __attribute__((ext_vector_type(8))) short     short8;
typedef __attribute__((ext_vector_type(8))) _Float16  half8;
typedef __attribute__((ext_vector_type(4))) float     float4v;

/* ---------------- common helpers ---------------- */

static __device__ __forceinline__ unsigned short f2bf(float f) {
    unsigned int x = __float_as_uint(f);
    unsigned int r = (x + 0x7fffu + ((x >> 16) & 1u)) >> 16;   // RNE
    return (unsigned short)r;
}

static __device__ __forceinline__ unsigned int h2mul(unsigned int a, unsigned int b) {
    union { unsigned int u; __half2 h; } A, B, R;
    A.u = a; B.u = b;
    R.h = __hmul2(A.h, B.h);
    return R.u;
}

static __device__ __forceinline__ uint4 h2mul4(uint4 a, uint4 b) {
    return make_uint4(h2mul(a.x, b.x), h2mul(a.y, b.y),
                      h2mul(a.z, b.z), h2mul(a.w, b.w));
}

static __device__ __forceinline__ float4v mfma16f(uint4 a, uint4 b, float4v c) {
    union { uint4 u; half8 h; } A, B;
    A.u = a; B.u = b;
    return __builtin_amdgcn_mfma_f32_16x16x32_f16(A.h, B.h, c, 0, 0, 0);
}

/* ================= f16 fast path ================= */

// Convert embeds (f32 -> f16, 64M elems) and W1 (block 0). BW-bound: ~384 MB.
__global__ __launch_bounds__(256)
void prep_f16(const float* __restrict__ embeds, const float* __restrict__ W1,
              __half* __restrict__ emb16, __half* __restrict__ W1h)
{
    const int nchunks = N_EMB * D / 8;          // 8M chunks of 8 floats
    const int stride  = gridDim.x * blockDim.x;
    for (int c = blockIdx.x * blockDim.x + threadIdx.x; c < nchunks; c += stride) {
        const float* src = embeds + (size_t)c * 8;
        float4 f0 = *(const float4*)(src);
        float4 f1 = *(const float4*)(src + 4);
        union { unsigned short s[8]; uint4 u; } o;
        o.s[0] = __half_as_ushort(__float2half(f0.x));
        o.s[1] = __half_as_ushort(__float2half(f0.y));
        o.s[2] = __half_as_ushort(__float2half(f0.z));
        o.s[3] = __half_as_ushort(__float2half(f0.w));
        o.s[4] = __half_as_ushort(__float2half(f1.x));
        o.s[5] = __half_as_ushort(__float2half(f1.y));
        o.s[6] = __half_as_ushort(__float2half(f1.z));
        o.s[7] = __half_as_ushort(__float2half(f1.w));
        *((uint4*)emb16 + c) = o.u;
    }
    if (blockIdx.x == 0)
        for (int i = threadIdx.x; i < 64 * 192; i += 256)
            W1h[i] = __float2half(W1[i]);
}

// Each wave: 32 pairs (2 m-tiles). Per pair only 4 gather loads (16B each,
// one per MFMA A-frag); u*v frags via v_pk_mul_f16 in registers. W1 f16 in
// global (24KB, L1-resident; every B-load line fully wave-consumed).
__global__ __launch_bounds__(256, 4)
void score_f16(const __half* __restrict__ emb,
               const int*    __restrict__ pos,
               const int*    __restrict__ neg,
               const __half* __restrict__ W1h,
               const float*  __restrict__ b1,
               const float*  __restrict__ W2,
               const float*  __restrict__ b2,
               float*        __restrict__ scores)
{
    const int t    = threadIdx.x;
    const int lane = t & 63;
    const int wave = t >> 6;
    const int c16  = lane & 15;
    const int quad = lane >> 4;
    const int pw   = blockIdx.x * PPB + wave * 32;

    const int p0 = pw + c16;
    const int p1 = pw + 16 + c16;
    int2 i0, i1;
    if (pw < E_PAIRS) {                       // wave-uniform branch
        i0 = ((const int2*)pos)[p0];
        i1 = ((const int2*)pos)[p1];
    } else {
        i0 = ((const int2*)neg)[p0 - E_PAIRS];
        i1 = ((const int2*)neg)[p1 - E_PAIRS];
    }

    const __half* u0p = emb + (long long)i0.x * D + quad * 8;
    const __half* v0p = emb + (long long)i0.y * D + quad * 8;
    const __half* u1p = emb + (long long)i1.x * D + quad * 8;
    const __half* v1p = emb + (long long)i1.y * D + quad * 8;

    uint4 a0[6], a1[6];
    a0[0] = *(const uint4*)(u0p);        // u, k slice [0,32)
    a0[1] = *(const uint4*)(u0p + 32);   // u, k slice [32,64)
    a0[2] = *(const uint4*)(v0p);
    a0[3] = *(const uint4*)(v0p + 32);
    a1[0] = *(const uint4*)(u1p);
    a1[1] = *(const uint4*)(u1p + 32);
    a1[2] = *(const uint4*)(v1p);
    a1[3] = *(const uint4*)(v1p + 32);
    a0[4] = h2mul4(a0[0], a0[2]);        // u*v
    a0[5] = h2mul4(a0[1], a0[3]);
    a1[4] = h2mul4(a1[0], a1[2]);
    a1[5] = h2mul4(a1[1], a1[3]);

    float4v acc[2][4];
    #pragma unroll
    for (int mt = 0; mt < 2; ++mt)
        #pragma unroll
        for (int nt = 0; nt < 4; ++nt)
            acc[mt][nt] = (float4v){0.f, 0.f, 0.f, 0.f};

    #pragma unroll
    for (int ks = 0; ks < 6; ++ks) {
        const int koff = ks * 32 + quad * 8;
        uint4 bfrag[4];
        #pragma unroll
        for (int nt = 0; nt < 4; ++nt)
            bfrag[nt] = *(const uint4*)(W1h + (nt * 16 + c16) * 192 + koff);
        #pragma unroll
        for (int nt = 0; nt < 4; ++nt) {
            acc[0][nt] = mfma16f(a0[ks], bfrag[nt], acc[0][nt]);
            acc[1][nt] = mfma16f(a1[ks], bfrag[nt], acc[1][nt]);
        }
    }

    float b1v[4], w2v[4];
    #pragma unroll
    for (int nt = 0; nt < 4; ++nt) {
        b1v[nt] = b1[nt * 16 + c16];
        w2v[nt] = W2[nt * 16 + c16];
    }
    const float b2v = b2[0];

    #pragma unroll
    for (int mt = 0; mt < 2; ++mt) {
        #pragma unroll
        for (int reg = 0; reg < 4; ++reg) {
            float s = 0.f;
            #pragma unroll
            for (int nt = 0; nt < 4; ++nt) {
                float h = acc[mt][nt][reg] + b1v[nt];
                s += (h > 0.f ? h : 0.f) * w2v[nt];
            }
            s += __shfl_xor(s, 1);
            s += __shfl_xor(s, 2);
            s += __shfl_xor(s, 4);
            s += __shfl_xor(s, 8);
            if (c16 == 0) {
                float sig = 1.f / (1.f + expf(-(s + b2v)));
                scores[pw + mt * 16 + quad * 4 + reg] = expf(sig);
            }
        }
    }
}

/* ================= f32 fallback path (round-1 kernel) ================= */

static __device__ __forceinline__ short8 pack8(float4 a, float4 b) {
    short8 r;
    r[0] = (short)f2bf(a.x); r[1] = (short)f2bf(a.y);
    r[2] = (short)f2bf(a.z); r[3] = (short)f2bf(a.w);
    r[4] = (short)f2bf(b.x); r[5] = (short)f2bf(b.y);
    r[6] = (short)f2bf(b.z); r[7] = (short)f2bf(b.w);
    return r;
}
static __device__ __forceinline__ float4 mul4(float4 a, float4 b) {
    return make_float4(a.x * b.x, a.y * b.y, a.z * b.z, a.w * b.w);
}
static __device__ __forceinline__ void load_frags(const float* __restrict__ embeds,
                                                  int ui, int vi, int quad, short8* fr)
{
    const float* up = embeds + (long long)ui * D + quad * 8;
    const float* vp = embeds + (long long)vi * D + quad * 8;
    float4 ua = *(const float4*)(up);
    float4 ub = *(const float4*)(up + 4);
    float4 uc = *(const float4*)(up + 32);
    float4 ud = *(const float4*)(up + 36);
    float4 va = *(const float4*)(vp);
    float4 vb = *(const float4*)(vp + 4);
    float4 vc = *(const float4*)(vp + 32);
    float4 vd = *(const float4*)(vp + 36);
    fr[0] = pack8(ua, ub); fr[1] = pack8(uc, ud);
    fr[2] = pack8(va, vb); fr[3] = pack8(vc, vd);
    fr[4] = pack8(mul4(ua, va), mul4(ub, vb));
    fr[5] = pack8(mul4(uc, vc), mul4(ud, vd));
}

__global__ __launch_bounds__(256)
void prep_w1bf(const float* __restrict__ W1, unsigned short* __restrict__ W1bf)
{
    int i = blockIdx.x * 256 + threadIdx.x;
    if (i < 64 * 192) W1bf[i] = f2bf(W1[i]);
}

__global__ __launch_bounds__(256, 4)
void score_f32(const float* __restrict__ embeds,
               const int*   __restrict__ pos,
               const int*   __restrict__ neg,
               const unsigned short* __restrict__ W1bf,
               const float* __restrict__ b1,
               const float* __restrict__ W2,
               const float* __restrict__ b2,
               float*       __restrict__ scores)
{
    const int t    = threadIdx.x;
    const int lane = t & 63;
    const int wave = t >> 6;
    const int c16  = lane & 15;
    const int quad = lane >> 4;
    const int pw   = blockIdx.x * PPB + wave * 32;

    const int p0 = pw + c16;
    const int p1 = pw + 16 + c16;
    int2 i0, i1;
    if (pw < E_PAIRS) {
        i0 = ((const int2*)pos)[p0];
        i1 = ((const int2*)pos)[p1];
    } else {
        i0 = ((const int2*)neg)[p0 - E_PAIRS];
        i1 = ((const int2*)neg)[p1 - E_PAIRS];
    }

    short8 a0[6], a1[6];
    load_frags(embeds, i0.x, i0.y, quad, a0);
    load_frags(embeds, i1.x, i1.y, quad, a1);

    float4v acc[2][4];
    #pragma unroll
    for (int mt = 0; mt < 2; ++mt)
        #pragma unroll
        for (int nt = 0; nt < 4; ++nt)
            acc[mt][nt] = (float4v){0.f, 0.f, 0.f, 0.f};

    #pragma unroll
    for (int ks = 0; ks < 6; ++ks) {
        const int koff = ks * 32 + quad * 8;
        short8 bfrag[4];
        #pragma unroll
        for (int nt = 0; nt < 4; ++nt)
            bfrag[nt] = *(const short8*)(W1bf + (nt * 16 + c16) * 192 + koff);
        #pragma unroll
        for (int nt = 0; nt < 4; ++nt) {
            acc[0][nt] = __builtin_amdgcn_mfma_f32_16x16x32_bf16(a0[ks], bfrag[nt], acc[0][nt], 0, 0, 0);
            acc[1][nt] = __builtin_amdgcn_mfma_f32_16x16x32_bf16(a1[ks], bfrag[nt], acc[1][nt], 0, 0, 0);
        }
    }

    float b1v[4], w2v[4];
    #pragma unroll
    for (int nt = 0; nt < 4; ++nt) {
        b1v[nt] = b1[nt * 16 + c16];
        w2v[nt] = W2[nt * 16 + c16];
    }
    const float b2v = b2[0];

    #pragma unroll
    for (int mt = 0; mt < 2; ++mt) {
        #pragma unroll
        for (int reg = 0; reg < 4; ++reg) {
            float s = 0.f;
            #pragma unroll
            for (int nt = 0; nt < 4; ++nt) {
                float h = acc[mt][nt][reg] + b1v[nt];
                s += (h > 0.f ? h : 0.f) * w2v[nt];
            }
            s += __shfl_xor(s, 1);
            s += __shfl_xor(s, 2);
            s += __shfl_xor(s, 4);
            s += __shfl_xor(s, 8);
            if (c16 == 0) {
                float sig = 1.f / (1.f + expf(-(s + b2v)));
                scores[pw + mt * 16 + quad * 4 + reg] = expf(sig);
            }
        }
    }
}

/* ================= reduction (shared) ================= */

__global__ __launch_bounds__(256)
void reduce_atomic(const float* __restrict__ scores, float* __restrict__ out)
{
    __shared__ float sdata[256];
    int e = blockIdx.x * 256 + threadIdx.x;    // e in [0, E_PAIRS)
    float pos_s = scores[e];
    const float* ns = scores + E_PAIRS + (size_t)e * K_NEG;
    float nsum = 0.f;
    #pragma unroll
    for (int c = 0; c < 4; ++c) {
        float4 v = *(const float4*)(ns + c * 4);
        nsum += v.x + v.y + v.z + v.w;
    }
    float term = pos_s / (pos_s + nsum + 1e-8f) + 1e-8f;
    sdata[threadIdx.x] = term;
    __syncthreads();
    for (int s = 128; s > 0; s >>= 1) {
        if (threadIdx.x < s) sdata[threadIdx.x] += sdata[threadIdx.x + s];
        __syncthreads();
    }
    if (threadIdx.x == 0) atomicAdd(out, -sdata[0]);
}

/* ================= launch ================= */

extern "C" void kernel_launch(void* const* d_in, const int* in_sizes, int n_in,
                              void* d_out, int out_size, void* d_ws, size_t ws_size,
                              hipStream_t stream)
{
    const float* embeds = (const float*)d_in[0];
    const int*   pos    = (const int*)d_in[1];
    const int*   neg    = (const int*)d_in[2];
    const float* W1     = (const float*)d_in[3];
    const float* b1     = (const float*)d_in[4];
    const float* W2     = (const float*)d_in[5];
    const float* b2     = (const float*)d_in[6];
    float* out = (float*)d_out;

    const size_t EMB16_BYTES = (size_t)N_EMB * D * 2;         /* 128,000,000 */
    const size_t need = EMB16_BYTES + (size_t)P_TOTAL * 4 + 64 * 192 * 2;

    hipMemsetAsync(out, 0, sizeof(float), stream);

    if (ws_size >= need) {
        __half* emb16  = (__half*)d_ws;
        float*  scores = (float*)((char*)d_ws + EMB16_BYTES);
        __half* W1h    = (__half*)(scores + P_TOTAL);

        prep_f16<<<2048, 256, 0, stream>>>(embeds, W1, emb16, W1h);
        score_f16<<<P_TOTAL / PPB, 256, 0, stream>>>(emb16, pos, neg, W1h, b1, W2, b2, scores);
        reduce_atomic<<<E_PAIRS / 256, 256, 0, stream>>>(scores, out);
    } else {
        float* scores = (float*)d_ws;
        unsigned short* W1bf = (unsigned short*)(scores + P_TOTAL);

        prep_w1bf<<<48, 256, 0, stream>>>(W1, W1bf);
        score_f32<<<P_TOTAL / PPB, 256, 0, stream>>>(embeds, pos, neg, W1bf, b1, W2, b2, scores);
        reduce_atomic<<<E_PAIRS / 256, 256, 0, stream>>>(scores, out);
    }
}

// Round 4
// 493.743 us; speedup vs baseline: 1.0382x; 1.0382x over previous
//
#include <hip/hip_runtime.h>
#include <hip/hip_fp16.h>
#include <math.h>

#define N_EMB   1000000
#define D       64
#define E_PAIRS 65536
#define K_NEG   16
#define P_TOTAL (E_PAIRS * (K_NEG + 1))   /* 1114112 */
#define PPB     128                        /* pairs per block (4 waves x 32 pairs) */

typedef __attribute__((ext_vector_type(8))) short     short8;
typedef __attribute__((ext_vector_type(8))) _Float16  half8;
typedef __attribute__((ext_vector_type(4))) float     float4v;

/* ---------------- common helpers ---------------- */

static __device__ __forceinline__ unsigned short f2bf(float f) {
    unsigned int x = __float_as_uint(f);
    unsigned int r = (x + 0x7fffu + ((x >> 16) & 1u)) >> 16;   // RNE
    return (unsigned short)r;
}

static __device__ __forceinline__ unsigned int h2mul(unsigned int a, unsigned int b) {
    union { unsigned int u; __half2 h; } A, B, R;
    A.u = a; B.u = b;
    R.h = __hmul2(A.h, B.h);
    return R.u;
}

static __device__ __forceinline__ uint4 h2mul4(uint4 a, uint4 b) {
    return make_uint4(h2mul(a.x, b.x), h2mul(a.y, b.y),
                      h2mul(a.z, b.z), h2mul(a.w, b.w));
}

static __device__ __forceinline__ float4v mfma16f(uint4 a, uint4 b, float4v c) {
    union { uint4 u; half8 h; } A, B;
    A.u = a; B.u = b;
    return __builtin_amdgcn_mfma_f32_16x16x32_f16(A.h, B.h, c, 0, 0, 0);
}

/* ================= f16 fast path ================= */

// Convert embeds f32 -> f16 (64M elems). NT loads for the f32 stream (never
// re-read: keep it OUT of L3); plain full-line stores for emb16 (WANT it
// resident in L3 so score's gathers are L3 hits).
__global__ __launch_bounds__(256)
void prep_f16(const float* __restrict__ embeds, const float* __restrict__ W1,
              __half* __restrict__ emb16, __half* __restrict__ W1h)
{
    const int nchunks = N_EMB * D / 8;          // 8M chunks of 8 floats
    const int stride  = gridDim.x * blockDim.x;
    for (int c = blockIdx.x * blockDim.x + threadIdx.x; c < nchunks; c += stride) {
        const float4v* src = (const float4v*)embeds + (size_t)c * 2;
        float4v f0 = __builtin_nontemporal_load(src);
        float4v f1 = __builtin_nontemporal_load(src + 1);
        union { unsigned short s[8]; uint4 u; } o;
        o.s[0] = __half_as_ushort(__float2half(f0[0]));
        o.s[1] = __half_as_ushort(__float2half(f0[1]));
        o.s[2] = __half_as_ushort(__float2half(f0[2]));
        o.s[3] = __half_as_ushort(__float2half(f0[3]));
        o.s[4] = __half_as_ushort(__float2half(f1[0]));
        o.s[5] = __half_as_ushort(__float2half(f1[1]));
        o.s[6] = __half_as_ushort(__float2half(f1[2]));
        o.s[7] = __half_as_ushort(__float2half(f1[3]));
        *((uint4*)emb16 + c) = o.u;
    }
    if (blockIdx.x == 0)
        for (int i = threadIdx.x; i < 64 * 192; i += 256)
            W1h[i] = __float2half(W1[i]);
}

// Each wave: 32 pairs (2 m-tiles). Per pair 4 gather loads (16B each, one per
// MFMA A-frag); u*v frags via v_pk_mul_f16 in registers. W1h L1-resident.
__global__ __launch_bounds__(256, 4)
void score_f16(const __half* __restrict__ emb,
               const int*    __restrict__ pos,
               const int*    __restrict__ neg,
               const __half* __restrict__ W1h,
               const float*  __restrict__ b1,
               const float*  __restrict__ W2,
               const float*  __restrict__ b2,
               float*        __restrict__ scores)
{
    const int t    = threadIdx.x;
    const int lane = t & 63;
    const int wave = t >> 6;
    const int c16  = lane & 15;
    const int quad = lane >> 4;
    const int pw   = blockIdx.x * PPB + wave * 32;

    const int p0 = pw + c16;
    const int p1 = pw + 16 + c16;
    int2 i0, i1;
    if (pw < E_PAIRS) {                       // wave-uniform branch
        i0 = ((const int2*)pos)[p0];
        i1 = ((const int2*)pos)[p1];
    } else {
        i0 = ((const int2*)neg)[p0 - E_PAIRS];
        i1 = ((const int2*)neg)[p1 - E_PAIRS];
    }

    const __half* u0p = emb + (long long)i0.x * D + quad * 8;
    const __half* v0p = emb + (long long)i0.y * D + quad * 8;
    const __half* u1p = emb + (long long)i1.x * D + quad * 8;
    const __half* v1p = emb + (long long)i1.y * D + quad * 8;

    uint4 a0[6], a1[6];
    a0[0] = *(const uint4*)(u0p);        // u, k slice [0,32)
    a0[1] = *(const uint4*)(u0p + 32);   // u, k slice [32,64)
    a0[2] = *(const uint4*)(v0p);
    a0[3] = *(const uint4*)(v0p + 32);
    a1[0] = *(const uint4*)(u1p);
    a1[1] = *(const uint4*)(u1p + 32);
    a1[2] = *(const uint4*)(v1p);
    a1[3] = *(const uint4*)(v1p + 32);
    a0[4] = h2mul4(a0[0], a0[2]);        // u*v
    a0[5] = h2mul4(a0[1], a0[3]);
    a1[4] = h2mul4(a1[0], a1[2]);
    a1[5] = h2mul4(a1[1], a1[3]);

    float4v acc[2][4];
    #pragma unroll
    for (int mt = 0; mt < 2; ++mt)
        #pragma unroll
        for (int nt = 0; nt < 4; ++nt)
            acc[mt][nt] = (float4v){0.f, 0.f, 0.f, 0.f};

    #pragma unroll
    for (int ks = 0; ks < 6; ++ks) {
        const int koff = ks * 32 + quad * 8;
        uint4 bfrag[4];
        #pragma unroll
        for (int nt = 0; nt < 4; ++nt)
            bfrag[nt] = *(const uint4*)(W1h + (nt * 16 + c16) * 192 + koff);
        #pragma unroll
        for (int nt = 0; nt < 4; ++nt) {
            acc[0][nt] = mfma16f(a0[ks], bfrag[nt], acc[0][nt]);
            acc[1][nt] = mfma16f(a1[ks], bfrag[nt], acc[1][nt]);
        }
    }

    float b1v[4], w2v[4];
    #pragma unroll
    for (int nt = 0; nt < 4; ++nt) {
        b1v[nt] = b1[nt * 16 + c16];
        w2v[nt] = W2[nt * 16 + c16];
    }
    const float b2v = b2[0];

    #pragma unroll
    for (int mt = 0; mt < 2; ++mt) {
        #pragma unroll
        for (int reg = 0; reg < 4; ++reg) {
            float s = 0.f;
            #pragma unroll
            for (int nt = 0; nt < 4; ++nt) {
                float h = acc[mt][nt][reg] + b1v[nt];
                s += (h > 0.f ? h : 0.f) * w2v[nt];
            }
            s += __shfl_xor(s, 1);
            s += __shfl_xor(s, 2);
            s += __shfl_xor(s, 4);
            s += __shfl_xor(s, 8);
            if (c16 == 0) {
                float sig = 1.f / (1.f + expf(-(s + b2v)));
                scores[pw + mt * 16 + quad * 4 + reg] = expf(sig);
            }
        }
    }
}

/* ================= f32 fallback path ================= */

static __device__ __forceinline__ short8 pack8(float4 a, float4 b) {
    short8 r;
    r[0] = (short)f2bf(a.x); r[1] = (short)f2bf(a.y);
    r[2] = (short)f2bf(a.z); r[3] = (short)f2bf(a.w);
    r[4] = (short)f2bf(b.x); r[5] = (short)f2bf(b.y);
    r[6] = (short)f2bf(b.z); r[7] = (short)f2bf(b.w);
    return r;
}
static __device__ __forceinline__ float4 mul4(float4 a, float4 b) {
    return make_float4(a.x * b.x, a.y * b.y, a.z * b.z, a.w * b.w);
}
static __device__ __forceinline__ void load_frags(const float* __restrict__ embeds,
                                                  int ui, int vi, int quad, short8* fr)
{
    const float* up = embeds + (long long)ui * D + quad * 8;
    const float* vp = embeds + (long long)vi * D + quad * 8;
    float4 ua = *(const float4*)(up);
    float4 ub = *(const float4*)(up + 4);
    float4 uc = *(const float4*)(up + 32);
    float4 ud = *(const float4*)(up + 36);
    float4 va = *(const float4*)(vp);
    float4 vb = *(const float4*)(vp + 4);
    float4 vc = *(const float4*)(vp + 32);
    float4 vd = *(const float4*)(vp + 36);
    fr[0] = pack8(ua, ub); fr[1] = pack8(uc, ud);
    fr[2] = pack8(va, vb); fr[3] = pack8(vc, vd);
    fr[4] = pack8(mul4(ua, va), mul4(ub, vb));
    fr[5] = pack8(mul4(uc, vc), mul4(ud, vd));
}

__global__ __launch_bounds__(256)
void prep_w1bf(const float* __restrict__ W1, unsigned short* __restrict__ W1bf)
{
    int i = blockIdx.x * 256 + threadIdx.x;
    if (i < 64 * 192) W1bf[i] = f2bf(W1[i]);
}

__global__ __launch_bounds__(256, 4)
void score_f32(const float* __restrict__ embeds,
               const int*   __restrict__ pos,
               const int*   __restrict__ neg,
               const unsigned short* __restrict__ W1bf,
               const float* __restrict__ b1,
               const float* __restrict__ W2,
               const float* __restrict__ b2,
               float*       __restrict__ scores)
{
    const int t    = threadIdx.x;
    const int lane = t & 63;
    const int wave = t >> 6;
    const int c16  = lane & 15;
    const int quad = lane >> 4;
    const int pw   = blockIdx.x * PPB + wave * 32;

    const int p0 = pw + c16;
    const int p1 = pw + 16 + c16;
    int2 i0, i1;
    if (pw < E_PAIRS) {
        i0 = ((const int2*)pos)[p0];
        i1 = ((const int2*)pos)[p1];
    } else {
        i0 = ((const int2*)neg)[p0 - E_PAIRS];
        i1 = ((const int2*)neg)[p1 - E_PAIRS];
    }

    short8 a0[6], a1[6];
    load_frags(embeds, i0.x, i0.y, quad, a0);
    load_frags(embeds, i1.x, i1.y, quad, a1);

    float4v acc[2][4];
    #pragma unroll
    for (int mt = 0; mt < 2; ++mt)
        #pragma unroll
        for (int nt = 0; nt < 4; ++nt)
            acc[mt][nt] = (float4v){0.f, 0.f, 0.f, 0.f};

    #pragma unroll
    for (int ks = 0; ks < 6; ++ks) {
        const int koff = ks * 32 + quad * 8;
        short8 bfrag[4];
        #pragma unroll
        for (int nt = 0; nt < 4; ++nt)
            bfrag[nt] = *(const short8*)(W1bf + (nt * 16 + c16) * 192 + koff);
        #pragma unroll
        for (int nt = 0; nt < 4; ++nt) {
            acc[0][nt] = __builtin_amdgcn_mfma_f32_16x16x32_bf16(a0[ks], bfrag[nt], acc[0][nt], 0, 0, 0);
            acc[1][nt] = __builtin_amdgcn_mfma_f32_16x16x32_bf16(a1[ks], bfrag[nt], acc[1][nt], 0, 0, 0);
        }
    }

    float b1v[4], w2v[4];
    #pragma unroll
    for (int nt = 0; nt < 4; ++nt) {
        b1v[nt] = b1[nt * 16 + c16];
        w2v[nt] = W2[nt * 16 + c16];
    }
    const float b2v = b2[0];

    #pragma unroll
    for (int mt = 0; mt < 2; ++mt) {
        #pragma unroll
        for (int reg = 0; reg < 4; ++reg) {
            float s = 0.f;
            #pragma unroll
            for (int nt = 0; nt < 4; ++nt) {
                float h = acc[mt][nt][reg] + b1v[nt];
                s += (h > 0.f ? h : 0.f) * w2v[nt];
            }
            s += __shfl_xor(s, 1);
            s += __shfl_xor(s, 2);
            s += __shfl_xor(s, 4);
            s += __shfl_xor(s, 8);
            if (c16 == 0) {
                float sig = 1.f / (1.f + expf(-(s + b2v)));
                scores[pw + mt * 16 + quad * 4 + reg] = expf(sig);
            }
        }
    }
}

/* ================= reduction ================= */

__global__ __launch_bounds__(256)
void reduce_atomic(const float* __restrict__ scores, float* __restrict__ out)
{
    __shared__ float sdata[256];
    int e = blockIdx.x * 256 + threadIdx.x;    // e in [0, E_PAIRS)
    float pos_s = scores[e];
    const float* ns = scores + E_PAIRS + (size_t)e * K_NEG;
    float nsum = 0.f;
    #pragma unroll
    for (int c = 0; c < 4; ++c) {
        float4 v = *(const float4*)(ns + c * 4);
        nsum += v.x + v.y + v.z + v.w;
    }
    float term = pos_s / (pos_s + nsum + 1e-8f) + 1e-8f;
    sdata[threadIdx.x] = term;
    __syncthreads();
    for (int s = 128; s > 0; s >>= 1) {
        if (threadIdx.x < s) sdata[threadIdx.x] += sdata[threadIdx.x + s];
        __syncthreads();
    }
    if (threadIdx.x == 0) atomicAdd(out, -sdata[0]);
}

/* ================= launch ================= */

extern "C" void kernel_launch(void* const* d_in, const int* in_sizes, int n_in,
                              void* d_out, int out_size, void* d_ws, size_t ws_size,
                              hipStream_t stream)
{
    const float* embeds = (const float*)d_in[0];
    const int*   pos    = (const int*)d_in[1];
    const int*   neg    = (const int*)d_in[2];
    const float* W1     = (const float*)d_in[3];
    const float* b1     = (const float*)d_in[4];
    const float* W2     = (const float*)d_in[5];
    const float* b2     = (const float*)d_in[6];
    float* out = (float*)d_out;

    const size_t EMB16_BYTES = (size_t)N_EMB * D * 2;         /* 128,000,000 */
    const size_t need = EMB16_BYTES + (size_t)P_TOTAL * 4 + 64 * 192 * 2;

    (void)hipMemsetAsync(out, 0, sizeof(float), stream);

    if (ws_size >= need) {
        __half* emb16  = (__half*)d_ws;
        float*  scores = (float*)((char*)d_ws + EMB16_BYTES);
        __half* W1h    = (__half*)(scores + P_TOTAL);

        prep_f16<<<4096, 256, 0, stream>>>(embeds, W1, emb16, W1h);
        score_f16<<<P_TOTAL / PPB, 256, 0, stream>>>(emb16, pos, neg, W1h, b1, W2, b2, scores);
        reduce_atomic<<<E_PAIRS / 256, 256, 0, stream>>>(scores, out);
    } else {
        float* scores = (float*)d_ws;
        unsigned short* W1bf = (unsigned short*)(scores + P_TOTAL);

        prep_w1bf<<<48, 256, 0, stream>>>(W1, W1bf);
        score_f32<<<P_TOTAL / PPB, 256, 0, stream>>>(embeds, pos, neg, W1bf, b1, W2, b2, scores);
        reduce_atomic<<<E_PAIRS / 256, 256, 0, stream>>>(scores, out);
    }
}

// Round 5
// 430.523 us; speedup vs baseline: 1.1906x; 1.1468x over previous
//
#include <hip/hip_runtime.h>
#include <hip/hip_fp16.h>
#include <math.h>

#define N_EMB   1000000
#define D       64
#define E_PAIRS 65536
#define K_NEG   16
#define P_TOTAL (E_PAIRS * (K_NEG + 1))   /* 1114112 */
#define NGROUPS (P_TOTAL / 32)            /* 34816 groups of 32 pairs */
#define GPW     4                          /* groups per wave */
#define SCORE_BLOCKS (NGROUPS / (4 * GPW)) /* 2176 */
#define W1S     200                        /* LDS k-stride (halves): 400B -> bank-conflict-free-ish */

typedef __attribute__((ext_vector_type(8))) short     short8;
typedef __attribute__((ext_vector_type(8))) _Float16  half8;
typedef __attribute__((ext_vector_type(4))) float     float4v;

/* ---------------- common helpers ---------------- */

static __device__ __forceinline__ unsigned short f2bf(float f) {
    unsigned int x = __float_as_uint(f);
    unsigned int r = (x + 0x7fffu + ((x >> 16) & 1u)) >> 16;   // RNE
    return (unsigned short)r;
}

static __device__ __forceinline__ unsigned int h2mul(unsigned int a, unsigned int b) {
    union { unsigned int u; __half2 h; } A, B, R;
    A.u = a; B.u = b;
    R.h = __hmul2(A.h, B.h);
    return R.u;
}

static __device__ __forceinline__ uint4 h2mul4(uint4 a, uint4 b) {
    return make_uint4(h2mul(a.x, b.x), h2mul(a.y, b.y),
                      h2mul(a.z, b.z), h2mul(a.w, b.w));
}

static __device__ __forceinline__ float4v mfma16f(uint4 a, uint4 b, float4v c) {
    union { uint4 u; half8 h; } A, B;
    A.u = a; B.u = b;
    return __builtin_amdgcn_mfma_f32_16x16x32_f16(A.h, B.h, c, 0, 0, 0);
}

/* ================= f16 fast path ================= */

// Convert embeds f32 -> f16 (64M elems). NT loads keep the never-re-read f32
// stream out of L3; plain stores leave emb16 L3-resident for score's gathers.
__global__ __launch_bounds__(256)
void prep_f16(const float* __restrict__ embeds, const float* __restrict__ W1,
              __half* __restrict__ emb16, __half* __restrict__ W1h)
{
    const int nchunks = N_EMB * D / 8;          // 8M chunks of 8 floats
    const int stride  = gridDim.x * blockDim.x;
    for (int c = blockIdx.x * blockDim.x + threadIdx.x; c < nchunks; c += stride) {
        const float4v* src = (const float4v*)embeds + (size_t)c * 2;
        float4v f0 = __builtin_nontemporal_load(src);
        float4v f1 = __builtin_nontemporal_load(src + 1);
        union { unsigned short s[8]; uint4 u; } o;
        o.s[0] = __half_as_ushort(__float2half(f0[0]));
        o.s[1] = __half_as_ushort(__float2half(f0[1]));
        o.s[2] = __half_as_ushort(__float2half(f0[2]));
        o.s[3] = __half_as_ushort(__float2half(f0[3]));
        o.s[4] = __half_as_ushort(__float2half(f1[0]));
        o.s[5] = __half_as_ushort(__float2half(f1[1]));
        o.s[6] = __half_as_ushort(__float2half(f1[2]));
        o.s[7] = __half_as_ushort(__float2half(f1[3]));
        *((uint4*)emb16 + c) = o.u;
    }
    if (blockIdx.x == 0)
        for (int i = threadIdx.x; i < 64 * 192; i += 256)
            W1h[i] = __float2half(W1[i]);
}

// Persistent waves, 2-deep gather pipeline. Each wave: GPW=4 groups of 32
// pairs. While computing group n, the 8 uint4 gathers for group n+1 are in
// flight. W1 lives in LDS (lgkmcnt) so compute never drains the vmcnt FIFO.

#define LOADIDX(gg, ii0, ii1) do {                                        \
    int _p0 = (gg) * 32 + c16;                                            \
    if ((gg) < E_PAIRS / 32) {                                            \
        ii0 = ((const int2*)pos)[_p0];                                    \
        ii1 = ((const int2*)pos)[_p0 + 16];                               \
    } else {                                                              \
        ii0 = ((const int2*)neg)[_p0 - E_PAIRS];                          \
        ii1 = ((const int2*)neg)[_p0 + 16 - E_PAIRS];                     \
    }                                                                     \
} while (0)

#define GATHER8(ii0, ii1, BUF) do {                                       \
    const __half* _u0 = emb + (long long)(ii0).x * D + quad * 8;          \
    const __half* _v0 = emb + (long long)(ii0).y * D + quad * 8;          \
    const __half* _u1 = emb + (long long)(ii1).x * D + quad * 8;          \
    const __half* _v1 = emb + (long long)(ii1).y * D + quad * 8;          \
    BUF##0 = *(const uint4*)(_u0);      BUF##1 = *(const uint4*)(_u0+32); \
    BUF##2 = *(const uint4*)(_v0);      BUF##3 = *(const uint4*)(_v0+32); \
    BUF##4 = *(const uint4*)(_u1);      BUF##5 = *(const uint4*)(_u1+32); \
    BUF##6 = *(const uint4*)(_v1);      BUF##7 = *(const uint4*)(_v1+32); \
} while (0)

#define COMPUTE_GROUP(BUF, gg) do {                                       \
    uint4 a0[6], a1[6];                                                   \
    a0[0]=BUF##0; a0[1]=BUF##1; a0[2]=BUF##2; a0[3]=BUF##3;               \
    a1[0]=BUF##4; a1[1]=BUF##5; a1[2]=BUF##6; a1[3]=BUF##7;               \
    a0[4]=h2mul4(a0[0],a0[2]); a0[5]=h2mul4(a0[1],a0[3]);                 \
    a1[4]=h2mul4(a1[0],a1[2]); a1[5]=h2mul4(a1[1],a1[3]);                 \
    float4v acc[2][4];                                                    \
    _Pragma("unroll")                                                     \
    for (int mt = 0; mt < 2; ++mt)                                        \
        _Pragma("unroll")                                                 \
        for (int nt = 0; nt < 4; ++nt)                                    \
            acc[mt][nt] = (float4v){0.f, 0.f, 0.f, 0.f};                  \
    _Pragma("unroll")                                                     \
    for (int ks = 0; ks < 6; ++ks) {                                      \
        const int koff = ks * 32 + quad * 8;                              \
        uint4 bfrag[4];                                                   \
        _Pragma("unroll")                                                 \
        for (int nt = 0; nt < 4; ++nt)                                    \
            bfrag[nt] = *(const uint4*)(&w1s[(nt*16 + c16)*W1S + koff]);  \
        _Pragma("unroll")                                                 \
        for (int nt = 0; nt < 4; ++nt) {                                  \
            acc[0][nt] = mfma16f(a0[ks], bfrag[nt], acc[0][nt]);          \
            acc[1][nt] = mfma16f(a1[ks], bfrag[nt], acc[1][nt]);          \
        }                                                                 \
    }                                                                     \
    _Pragma("unroll")                                                     \
    for (int mt = 0; mt < 2; ++mt) {                                      \
        _Pragma("unroll")                                                 \
        for (int reg = 0; reg < 4; ++reg) {                               \
            float s = 0.f;                                                \
            _Pragma("unroll")                                             \
            for (int nt = 0; nt < 4; ++nt) {                              \
                float h = acc[mt][nt][reg] + b1v[nt];                     \
                s += (h > 0.f ? h : 0.f) * w2v[nt];                       \
            }                                                             \
            s += __shfl_xor(s, 1);                                        \
            s += __shfl_xor(s, 2);                                        \
            s += __shfl_xor(s, 4);                                        \
            s += __shfl_xor(s, 8);                                        \
            if (c16 == 0) {                                               \
                float sig = 1.f / (1.f + expf(-(s + b2v)));               \
                scores[(gg)*32 + mt*16 + quad*4 + reg] = expf(sig);       \
            }                                                             \
        }                                                                 \
    }                                                                     \
} while (0)

__global__ __launch_bounds__(256, 3)
void score_f16(const __half* __restrict__ emb,
               const int*    __restrict__ pos,
               const int*    __restrict__ neg,
               const __half* __restrict__ W1h,
               const float*  __restrict__ b1,
               const float*  __restrict__ W2,
               const float*  __restrict__ b2,
               float*        __restrict__ scores)
{
    __shared__ __half w1s[64 * W1S];

    const int t    = threadIdx.x;
    const int lane = t & 63;
    const int wave = t >> 6;
    const int c16  = lane & 15;
    const int quad = lane >> 4;

    // ---- stage W1 (f16) into padded LDS: [n(64)][k stride 200] ----
    for (int idx = t * 8; idx < 64 * 192; idx += 256 * 8) {
        int n = idx / 192, k = idx - n * 192;
        *(uint4*)(&w1s[n * W1S + k]) = *(const uint4*)(W1h + idx);
    }
    __syncthreads();

    // ---- epilogue constants ----
    float b1v[4], w2v[4];
    #pragma unroll
    for (int nt = 0; nt < 4; ++nt) {
        b1v[nt] = b1[nt * 16 + c16];
        w2v[nt] = W2[nt * 16 + c16];
    }
    const float b2v = b2[0];

    // ---- 4 groups per wave, software-pipelined 2 deep ----
    const int gw = blockIdx.x * 4 + wave;    // global wave id
    const int g0 = gw * GPW;

    int2 ia0, ib0, ia1, ib1, ia2, ib2, ia3, ib3;
    uint4 A0, A1, A2, A3, A4, A5, A6, A7;
    uint4 B0, B1, B2, B3, B4, B5, B6, B7;

    LOADIDX(g0 + 0, ia0, ib0);
    LOADIDX(g0 + 1, ia1, ib1);
    GATHER8(ia0, ib0, A);
    GATHER8(ia1, ib1, B);
    LOADIDX(g0 + 2, ia2, ib2);
    COMPUTE_GROUP(A, g0 + 0);
    GATHER8(ia2, ib2, A);
    LOADIDX(g0 + 3, ia3, ib3);
    COMPUTE_GROUP(B, g0 + 1);
    GATHER8(ia3, ib3, B);
    COMPUTE_GROUP(A, g0 + 2);
    COMPUTE_GROUP(B, g0 + 3);
}

/* ================= f32 fallback path ================= */

static __device__ __forceinline__ short8 pack8(float4 a, float4 b) {
    short8 r;
    r[0] = (short)f2bf(a.x); r[1] = (short)f2bf(a.y);
    r[2] = (short)f2bf(a.z); r[3] = (short)f2bf(a.w);
    r[4] = (short)f2bf(b.x); r[5] = (short)f2bf(b.y);
    r[6] = (short)f2bf(b.z); r[7] = (short)f2bf(b.w);
    return r;
}
static __device__ __forceinline__ float4 mul4(float4 a, float4 b) {
    return make_float4(a.x * b.x, a.y * b.y, a.z * b.z, a.w * b.w);
}
static __device__ __forceinline__ void load_frags(const float* __restrict__ embeds,
                                                  int ui, int vi, int quad, short8* fr)
{
    const float* up = embeds + (long long)ui * D + quad * 8;
    const float* vp = embeds + (long long)vi * D + quad * 8;
    float4 ua = *(const float4*)(up);
    float4 ub = *(const float4*)(up + 4);
    float4 uc = *(const float4*)(up + 32);
    float4 ud = *(const float4*)(up + 36);
    float4 va = *(const float4*)(vp);
    float4 vb = *(const float4*)(vp + 4);
    float4 vc = *(const float4*)(vp + 32);
    float4 vd = *(const float4*)(vp + 36);
    fr[0] = pack8(ua, ub); fr[1] = pack8(uc, ud);
    fr[2] = pack8(va, vb); fr[3] = pack8(vc, vd);
    fr[4] = pack8(mul4(ua, va), mul4(ub, vb));
    fr[5] = pack8(mul4(uc, vc), mul4(ud, vd));
}

__global__ __launch_bounds__(256)
void prep_w1bf(const float* __restrict__ W1, unsigned short* __restrict__ W1bf)
{
    int i = blockIdx.x * 256 + threadIdx.x;
    if (i < 64 * 192) W1bf[i] = f2bf(W1[i]);
}

__global__ __launch_bounds__(256, 4)
void score_f32(const float* __restrict__ embeds,
               const int*   __restrict__ pos,
               const int*   __restrict__ neg,
               const unsigned short* __restrict__ W1bf,
               const float* __restrict__ b1,
               const float* __restrict__ W2,
               const float* __restrict__ b2,
               float*       __restrict__ scores)
{
    const int t    = threadIdx.x;
    const int lane = t & 63;
    const int wave = t >> 6;
    const int c16  = lane & 15;
    const int quad = lane >> 4;
    const int pw   = blockIdx.x * 128 + wave * 32;

    const int p0 = pw + c16;
    const int p1 = pw + 16 + c16;
    int2 i0, i1;
    if (pw < E_PAIRS) {
        i0 = ((const int2*)pos)[p0];
        i1 = ((const int2*)pos)[p1];
    } else {
        i0 = ((const int2*)neg)[p0 - E_PAIRS];
        i1 = ((const int2*)neg)[p1 - E_PAIRS];
    }

    short8 a0[6], a1[6];
    load_frags(embeds, i0.x, i0.y, quad, a0);
    load_frags(embeds, i1.x, i1.y, quad, a1);

    float4v acc[2][4];
    #pragma unroll
    for (int mt = 0; mt < 2; ++mt)
        #pragma unroll
        for (int nt = 0; nt < 4; ++nt)
            acc[mt][nt] = (float4v){0.f, 0.f, 0.f, 0.f};

    #pragma unroll
    for (int ks = 0; ks < 6; ++ks) {
        const int koff = ks * 32 + quad * 8;
        short8 bfrag[4];
        #pragma unroll
        for (int nt = 0; nt < 4; ++nt)
            bfrag[nt] = *(const short8*)(W1bf + (nt * 16 + c16) * 192 + koff);
        #pragma unroll
        for (int nt = 0; nt < 4; ++nt) {
            acc[0][nt] = __builtin_amdgcn_mfma_f32_16x16x32_bf16(a0[ks], bfrag[nt], acc[0][nt], 0, 0, 0);
            acc[1][nt] = __builtin_amdgcn_mfma_f32_16x16x32_bf16(a1[ks], bfrag[nt], acc[1][nt], 0, 0, 0);
        }
    }

    float b1v[4], w2v[4];
    #pragma unroll
    for (int nt = 0; nt < 4; ++nt) {
        b1v[nt] = b1[nt * 16 + c16];
        w2v[nt] = W2[nt * 16 + c16];
    }
    const float b2v = b2[0];

    #pragma unroll
    for (int mt = 0; mt < 2; ++mt) {
        #pragma unroll
        for (int reg = 0; reg < 4; ++reg) {
            float s = 0.f;
            #pragma unroll
            for (int nt = 0; nt < 4; ++nt) {
                float h = acc[mt][nt][reg] + b1v[nt];
                s += (h > 0.f ? h : 0.f) * w2v[nt];
            }
            s += __shfl_xor(s, 1);
            s += __shfl_xor(s, 2);
            s += __shfl_xor(s, 4);
            s += __shfl_xor(s, 8);
            if (c16 == 0) {
                float sig = 1.f / (1.f + expf(-(s + b2v)));
                scores[pw + mt * 16 + quad * 4 + reg] = expf(sig);
            }
        }
    }
}

/* ================= reduction ================= */

__global__ __launch_bounds__(256)
void reduce_atomic(const float* __restrict__ scores, float* __restrict__ out)
{
    __shared__ float sdata[256];
    int e = blockIdx.x * 256 + threadIdx.x;    // e in [0, E_PAIRS)
    float pos_s = scores[e];
    const float* ns = scores + E_PAIRS + (size_t)e * K_NEG;
    float nsum = 0.f;
    #pragma unroll
    for (int c = 0; c < 4; ++c) {
        float4 v = *(const float4*)(ns + c * 4);
        nsum += v.x + v.y + v.z + v.w;
    }
    float term = pos_s / (pos_s + nsum + 1e-8f) + 1e-8f;
    sdata[threadIdx.x] = term;
    __syncthreads();
    for (int s = 128; s > 0; s >>= 1) {
        if (threadIdx.x < s) sdata[threadIdx.x] += sdata[threadIdx.x + s];
        __syncthreads();
    }
    if (threadIdx.x == 0) atomicAdd(out, -sdata[0]);
}

/* ================= launch ================= */

extern "C" void kernel_launch(void* const* d_in, const int* in_sizes, int n_in,
                              void* d_out, int out_size, void* d_ws, size_t ws_size,
                              hipStream_t stream)
{
    const float* embeds = (const float*)d_in[0];
    const int*   pos    = (const int*)d_in[1];
    const int*   neg    = (const int*)d_in[2];
    const float* W1     = (const float*)d_in[3];
    const float* b1     = (const float*)d_in[4];
    const float* W2     = (const float*)d_in[5];
    const float* b2     = (const float*)d_in[6];
    float* out = (float*)d_out;

    const size_t EMB16_BYTES = (size_t)N_EMB * D * 2;         /* 128,000,000 */
    const size_t need = EMB16_BYTES + (size_t)P_TOTAL * 4 + 64 * 192 * 2;

    (void)hipMemsetAsync(out, 0, sizeof(float), stream);

    if (ws_size >= need) {
        __half* emb16  = (__half*)d_ws;
        float*  scores = (float*)((char*)d_ws + EMB16_BYTES);
        __half* W1h    = (__half*)(scores + P_TOTAL);

        prep_f16<<<4096, 256, 0, stream>>>(embeds, W1, emb16, W1h);
        score_f16<<<SCORE_BLOCKS, 256, 0, stream>>>(emb16, pos, neg, W1h, b1, W2, b2, scores);
        reduce_atomic<<<E_PAIRS / 256, 256, 0, stream>>>(scores, out);
    } else {
        float* scores = (float*)d_ws;
        unsigned short* W1bf = (unsigned short*)(scores + P_TOTAL);

        prep_w1bf<<<48, 256, 0, stream>>>(W1, W1bf);
        score_f32<<<P_TOTAL / 128, 256, 0, stream>>>(embeds, pos, neg, W1bf, b1, W2, b2, scores);
        reduce_atomic<<<E_PAIRS / 256, 256, 0, stream>>>(scores, out);
    }
}